// Round 5
// baseline (164.466 us; speedup 1.0000x reference)
//
#include <hip/hip_runtime.h>
#include <hip/hip_bf16.h>

#define NROWS 131072
#define KIN   784
#define H1N   128
#define H2N   64
#define OUTN  10

// chunked weight layouts: w1c[kb][col][8] with kb = k/8  (k in [0,800))
#define W1C_ELEMS (100 * 128 * 8)   // 102400
#define W2C_ELEMS (16 * 64 * 8)     // 8192
#define W3_ELEMS  (16 * 64)         // 1024

typedef short s16x8 __attribute__((ext_vector_type(8)));
typedef float f32x4 __attribute__((ext_vector_type(4)));

typedef __hip_bfloat16 bf16;

static __device__ __forceinline__ short b2s(float f) {
    bf16 h = __float2bfloat16(f);
    return *reinterpret_cast<short*>(&h);
}

static __device__ __forceinline__ s16x8 cvt8(f32x4 a, f32x4 b) {
    s16x8 r;
    r[0] = b2s(a[0]); r[1] = b2s(a[1]); r[2] = b2s(a[2]); r[3] = b2s(a[3]);
    r[4] = b2s(b[0]); r[5] = b2s(b[1]); r[6] = b2s(b[2]); r[7] = b2s(b[3]);
    return r;
}

// ---------------- dequant: int4(int32) * f32 scale -> bf16 (chunked layouts) --
__global__ __launch_bounds__(256) void dequant_kernel(
    const int* __restrict__ w1q, const float* __restrict__ s1,
    const int* __restrict__ w2q, const float* __restrict__ s2,
    const int* __restrict__ w3q, const float* __restrict__ s3,
    bf16* __restrict__ w1c, bf16* __restrict__ w2c, bf16* __restrict__ w3d)
{
    const int total = W1C_ELEMS + W2C_ELEMS + W3_ELEMS;
    for (int i = blockIdx.x * blockDim.x + threadIdx.x; i < total;
         i += gridDim.x * blockDim.x) {
        if (i < W1C_ELEMS) {
            int kb = i >> 10, rem = i & 1023;
            int col = rem >> 3, j = rem & 7;
            int k = kb * 8 + j;
            float v = 0.0f;
            if (k < KIN) v = (float)w1q[col * KIN + k] * s1[col];
            w1c[i] = __float2bfloat16(v);
        } else if (i < W1C_ELEMS + W2C_ELEMS) {
            int t = i - W1C_ELEMS;
            int kb = t >> 9, rem = t & 511;
            int col = rem >> 3, j = rem & 7;
            int k = kb * 8 + j;
            w2c[t] = __float2bfloat16((float)w2q[col * H1N + k] * s2[col]);
        } else {
            int t = i - W1C_ELEMS - W2C_ELEMS;
            int r = t >> 6, c = t & 63;
            float v = 0.0f;
            if (r < OUTN) v = (float)w3q[r * H2N + c] * s3[r];
            w3d[t] = __float2bfloat16(v);
        }
    }
}

// ---------------- fused MLP ------------------------------------------------
// 256 threads (4 waves), BM=128 rows/block, wave w owns rows w*32..w*32+31.
// LDS = 33.8 KB -> 4 blocks/CU, grid 1024 = one balanced round.
// Layer1: 2-deep register ping-pong prefetch of raw f32 x (8 loads in flight
// per wave), cvt->bf16 in-reg, MFMA 16x16x32 bf16, k-chunked W1.
__global__ __launch_bounds__(256, 4) void mlp_kernel(
    const float* __restrict__ x,
    const bf16*  __restrict__ w1c,
    const bf16*  __restrict__ w2c,
    const bf16*  __restrict__ w3d,
    const float* __restrict__ b1,
    const float* __restrict__ b2,
    const float* __restrict__ b3,
    float* __restrict__ out)
{
    __shared__ __align__(16) short h1[128][132];   // 33,792 B; phases overlay here

    const int tid  = threadIdx.x;
    const int lane = tid & 63;
    const int wv   = tid >> 6;      // wave 0..3
    const int r16  = lane & 15;
    const int kg   = lane >> 4;     // 0..3
    const int kgo  = kg * 8;

    const long long row0 = (long long)blockIdx.x * 128 + wv * 32;
    const float* xa0 = x + (row0 + r16) * (long long)KIN + kgo;
    const float* xa1 = xa0 + 16LL * KIN;

    // ---- layer 1: [128 x 784] @ [784 x 128], 25 k-iters of 32 ----
    f32x4 acc1[2][8];
#pragma unroll
    for (int i = 0; i < 2; ++i)
#pragma unroll
        for (int j = 0; j < 8; ++j) acc1[i][j] = (f32x4){0.f, 0.f, 0.f, 0.f};

    // ping-pong prefetch registers: pa = even iters, pb = odd iters
    f32x4 pa0, pa1, pa2, pa3, pb0, pb1, pb2, pb3;
    pa0 = *(const f32x4*)(xa0);       pa1 = *(const f32x4*)(xa0 + 4);
    pa2 = *(const f32x4*)(xa1);       pa3 = *(const f32x4*)(xa1 + 4);
    pb0 = *(const f32x4*)(xa0 + 32);  pb1 = *(const f32x4*)(xa0 + 36);
    pb2 = *(const f32x4*)(xa1 + 32);  pb3 = *(const f32x4*)(xa1 + 36);

    const bf16* bpA = w1c + (size_t)kg * 1024 + (size_t)r16 * 8;
    const bf16* bpB = bpA + 4096;

#pragma unroll 1
    for (int t = 0; t < 12; ++t) {
        // ---- even iter 2t: consume pa, reload pa <- iter 2t+2 ----
        {
            s16x8 a0 = cvt8(pa0, pa1);
            s16x8 a1 = cvt8(pa2, pa3);
            const int idx = 2 * t + 2;
            const int nx = idx * 32;
            if (idx < 24) {
                pa0 = *(const f32x4*)(xa0 + nx);
                pa1 = *(const f32x4*)(xa0 + nx + 4);
                pa2 = *(const f32x4*)(xa1 + nx);
                pa3 = *(const f32x4*)(xa1 + nx + 4);
            } else {    // idx == 24: k0=768, only kg 0,1 in range
                if (kg < 2) {
                    pa0 = *(const f32x4*)(xa0 + nx);
                    pa1 = *(const f32x4*)(xa0 + nx + 4);
                    pa2 = *(const f32x4*)(xa1 + nx);
                    pa3 = *(const f32x4*)(xa1 + nx + 4);
                } else {
                    pa0 = (f32x4){0.f,0.f,0.f,0.f}; pa1 = pa0; pa2 = pa0; pa3 = pa0;
                }
            }
#pragma unroll
            for (int nj = 0; nj < 8; ++nj) {
                s16x8 b = *(const s16x8*)(bpA + nj * 128);
                acc1[0][nj] = __builtin_amdgcn_mfma_f32_16x16x32_bf16(a0, b, acc1[0][nj], 0, 0, 0);
                acc1[1][nj] = __builtin_amdgcn_mfma_f32_16x16x32_bf16(a1, b, acc1[1][nj], 0, 0, 0);
            }
            bpA += 8192;
        }
        // ---- odd iter 2t+1: consume pb, reload pb <- iter 2t+3 ----
        {
            s16x8 a0 = cvt8(pb0, pb1);
            s16x8 a1 = cvt8(pb2, pb3);
            const int idx = 2 * t + 3;
            const int nx = idx * 32;
            if (idx < 24) {
                pb0 = *(const f32x4*)(xa0 + nx);
                pb1 = *(const f32x4*)(xa0 + nx + 4);
                pb2 = *(const f32x4*)(xa1 + nx);
                pb3 = *(const f32x4*)(xa1 + nx + 4);
            }   // idx 25: leave pb dead (never consumed)
#pragma unroll
            for (int nj = 0; nj < 8; ++nj) {
                s16x8 b = *(const s16x8*)(bpB + nj * 128);
                acc1[0][nj] = __builtin_amdgcn_mfma_f32_16x16x32_bf16(a0, b, acc1[0][nj], 0, 0, 0);
                acc1[1][nj] = __builtin_amdgcn_mfma_f32_16x16x32_bf16(a1, b, acc1[1][nj], 0, 0, 0);
            }
            bpB += 8192;
        }
    }
    {   // ---- tail iter 24 (k0=768): consume pa (masked-loaded above) ----
        s16x8 a0 = cvt8(pa0, pa1);
        s16x8 a1 = cvt8(pa2, pa3);
#pragma unroll
        for (int nj = 0; nj < 8; ++nj) {
            s16x8 b = *(const s16x8*)(bpA + nj * 128);  // zero-padded weights
            acc1[0][nj] = __builtin_amdgcn_mfma_f32_16x16x32_bf16(a0, b, acc1[0][nj], 0, 0, 0);
            acc1[1][nj] = __builtin_amdgcn_mfma_f32_16x16x32_bf16(a1, b, acc1[1][nj], 0, 0, 0);
        }
    }

    // bias + relu -> h1 (D layout: col = lane&15, row = (lane>>4)*4 + r)
#pragma unroll
    for (int mi = 0; mi < 2; ++mi)
#pragma unroll
        for (int nj = 0; nj < 8; ++nj) {
            const int col = nj * 16 + r16;
            const float bb = b1[col];
#pragma unroll
            for (int r = 0; r < 4; ++r) {
                const int row = wv * 32 + mi * 16 + kg * 4 + r;
                h1[row][col] = b2s(fmaxf(acc1[mi][nj][r] + bb, 0.0f));
            }
        }
    __syncthreads();

    // ---- layer 2: [128 x 128] @ [128 x 64] ----
    f32x4 acc2[2][4];
#pragma unroll
    for (int i = 0; i < 2; ++i)
#pragma unroll
        for (int j = 0; j < 4; ++j) acc2[i][j] = (f32x4){0.f, 0.f, 0.f, 0.f};

#pragma unroll
    for (int it = 0; it < 4; ++it) {
        const int kk = it * 32 + kgo;
        s16x8 a0 = *(const s16x8*)&h1[wv * 32 + r16][kk];
        s16x8 a1 = *(const s16x8*)&h1[wv * 32 + 16 + r16][kk];
        const bf16* bp2 = w2c + (size_t)(it * 4 + kg) * 512 + (size_t)r16 * 8;
#pragma unroll
        for (int nj = 0; nj < 4; ++nj) {
            s16x8 b = *(const s16x8*)(bp2 + nj * 128);
            acc2[0][nj] = __builtin_amdgcn_mfma_f32_16x16x32_bf16(a0, b, acc2[0][nj], 0, 0, 0);
            acc2[1][nj] = __builtin_amdgcn_mfma_f32_16x16x32_bf16(a1, b, acc2[1][nj], 0, 0, 0);
        }
    }
    __syncthreads();   // all h1 reads done -> safe to overlay

    short (*h2)[68] = (short(*)[68])&h1[0][0];   // 17,408 B overlay
#pragma unroll
    for (int mi = 0; mi < 2; ++mi)
#pragma unroll
        for (int nj = 0; nj < 4; ++nj) {
            const int col = nj * 16 + r16;
            const float bb = b2[col];
#pragma unroll
            for (int r = 0; r < 4; ++r) {
                const int row = wv * 32 + mi * 16 + kg * 4 + r;
                h2[row][col] = b2s(fmaxf(acc2[mi][nj][r] + bb, 0.0f));
            }
        }
    __syncthreads();

    // ---- layer 3: [128 x 64] @ [64 x 16] (rows 10..15 of W3 are zero) ----
    f32x4 acc3[2];
#pragma unroll
    for (int i = 0; i < 2; ++i) acc3[i] = (f32x4){0.f, 0.f, 0.f, 0.f};

#pragma unroll
    for (int it = 0; it < 2; ++it) {
        const int kk = it * 32 + kgo;
        s16x8 a0 = *(const s16x8*)&h2[wv * 32 + r16][kk];
        s16x8 a1 = *(const s16x8*)&h2[wv * 32 + 16 + r16][kk];
        s16x8 b  = *(const s16x8*)(w3d + r16 * H2N + kk);
        acc3[0] = __builtin_amdgcn_mfma_f32_16x16x32_bf16(a0, b, acc3[0], 0, 0, 0);
        acc3[1] = __builtin_amdgcn_mfma_f32_16x16x32_bf16(a1, b, acc3[1], 0, 0, 0);
    }
    __syncthreads();   // all h2 reads done -> safe to overlay

    float* ob = (float*)&h1[0][0];   // 5,120 B
    const float bb3 = (r16 < OUTN) ? b3[r16] : 0.0f;
#pragma unroll
    for (int mi = 0; mi < 2; ++mi)
#pragma unroll
        for (int r = 0; r < 4; ++r) {
            const int row = wv * 32 + mi * 16 + kg * 4 + r;
            if (r16 < OUTN) ob[row * OUTN + r16] = acc3[mi][r] + bb3;
        }
    __syncthreads();

    const long long obase = (long long)blockIdx.x * 128 * OUTN;
    for (int i = tid; i < 128 * OUTN; i += 256) out[obase + i] = ob[i];
}

extern "C" void kernel_launch(void* const* d_in, const int* in_sizes, int n_in,
                              void* d_out, int out_size, void* d_ws, size_t ws_size,
                              hipStream_t stream) {
    const float* x   = (const float*)d_in[0];
    const int*   w1q = (const int*)d_in[1];
    const float* s1  = (const float*)d_in[2];
    const float* b1  = (const float*)d_in[3];
    const int*   w2q = (const int*)d_in[4];
    const float* s2  = (const float*)d_in[5];
    const float* b2  = (const float*)d_in[6];
    const int*   w3q = (const int*)d_in[7];
    const float* s3  = (const float*)d_in[8];
    const float* b3  = (const float*)d_in[9];
    float* out = (float*)d_out;

    bf16* w1c = (bf16*)d_ws;              // [100][128][8]
    bf16* w2c = w1c + W1C_ELEMS;          // [16][64][8]
    bf16* w3d = w2c + W2C_ELEMS;          // [16][64]

    dequant_kernel<<<128, 256, 0, stream>>>(w1q, s1, w2q, s2, w3q, s3, w1c, w2c, w3d);
    mlp_kernel<<<NROWS / 128, 256, 0, stream>>>(x, w1c, w2c, w3d, b1, b2, b3, out);
}

// Round 6
// 154.704 us; speedup vs baseline: 1.0631x; 1.0631x over previous
//
#include <hip/hip_runtime.h>
#include <hip/hip_bf16.h>

#define NROWS 131072
#define KIN   784
#define H1N   128
#define H2N   64
#define OUTN  10

// chunked weight layouts: w1c[kb][col][8] with kb = k/8  (k in [0,800))
#define W1C_ELEMS (100 * 128 * 8)   // 102400
#define W2C_ELEMS (16 * 64 * 8)     // 8192
#define W3_ELEMS  (16 * 64)         // 1024

typedef short s16x8 __attribute__((ext_vector_type(8)));
typedef float f32x4 __attribute__((ext_vector_type(4)));

typedef __hip_bfloat16 bf16;

static __device__ __forceinline__ short b2s(float f) {
    bf16 h = __float2bfloat16(f);
    return *reinterpret_cast<short*>(&h);
}

static __device__ __forceinline__ s16x8 cvt8(f32x4 a, f32x4 b) {
    s16x8 r;
    r[0] = b2s(a[0]); r[1] = b2s(a[1]); r[2] = b2s(a[2]); r[3] = b2s(a[3]);
    r[4] = b2s(b[0]); r[5] = b2s(b[1]); r[6] = b2s(b[2]); r[7] = b2s(b[3]);
    return r;
}

// ---------------- dequant: int4(int32) * f32 scale -> bf16 (chunked layouts) --
__global__ __launch_bounds__(256) void dequant_kernel(
    const int* __restrict__ w1q, const float* __restrict__ s1,
    const int* __restrict__ w2q, const float* __restrict__ s2,
    const int* __restrict__ w3q, const float* __restrict__ s3,
    bf16* __restrict__ w1c, bf16* __restrict__ w2c, bf16* __restrict__ w3d)
{
    const int total = W1C_ELEMS + W2C_ELEMS + W3_ELEMS;
    for (int i = blockIdx.x * blockDim.x + threadIdx.x; i < total;
         i += gridDim.x * blockDim.x) {
        if (i < W1C_ELEMS) {
            int kb = i >> 10, rem = i & 1023;
            int col = rem >> 3, j = rem & 7;
            int k = kb * 8 + j;
            float v = 0.0f;
            if (k < KIN) v = (float)w1q[col * KIN + k] * s1[col];
            w1c[i] = __float2bfloat16(v);
        } else if (i < W1C_ELEMS + W2C_ELEMS) {
            int t = i - W1C_ELEMS;
            int kb = t >> 9, rem = t & 511;
            int col = rem >> 3, j = rem & 7;
            int k = kb * 8 + j;
            w2c[t] = __float2bfloat16((float)w2q[col * H1N + k] * s2[col]);
        } else {
            int t = i - W1C_ELEMS - W2C_ELEMS;
            int r = t >> 6, c = t & 63;
            float v = 0.0f;
            if (r < OUTN) v = (float)w3q[r * H2N + c] * s3[r];
            w3d[t] = __float2bfloat16(v);
        }
    }
}

// ---------------- fused MLP ------------------------------------------------
// 256 threads (4 waves), BM=64 rows/block, wave w owns rows w*16..w*16+15.
// Layer1: BK=128 — each wave reads a 512-B contiguous k-panel per row per
// visit (4x longer DRAM runs, half the concurrent row-streams vs r4) into
// registers, cvt->bf16, 32 MFMAs/iter. All LDS is wave-private (per-wave
// arena) -> NO barriers anywhere. fp32 accum throughout.
__global__ __launch_bounds__(256, 4) void mlp_kernel(
    const float* __restrict__ x,
    const bf16*  __restrict__ w1c,
    const bf16*  __restrict__ w2c,
    const bf16*  __restrict__ w3d,
    const float* __restrict__ b1,
    const float* __restrict__ b2,
    const float* __restrict__ b3,
    float* __restrict__ out)
{
    __shared__ __align__(16) char arena[4][4224];   // per-wave: h1[16][132] shorts

    const int tid  = threadIdx.x;
    const int lane = tid & 63;
    const int wv   = tid >> 6;      // wave 0..3
    const int r16  = lane & 15;
    const int kg   = lane >> 4;     // 0..3
    const int kgo  = kg * 8;

    const long long row0 = (long long)blockIdx.x * 64 + wv * 16;
    const float* xa = x + (row0 + r16) * (long long)KIN;

    // ---- layer 1: [64 x 784] @ [784 x 128]; 6 iters of BK=128 + tail 16 ----
    f32x4 acc1[8];
#pragma unroll
    for (int j = 0; j < 8; ++j) acc1[j] = (f32x4){0.f, 0.f, 0.f, 0.f};

#pragma unroll 1
    for (int it = 0; it < 6; ++it) {
        const float* p = xa + it * 128 + kgo;
        // 512 B per row in one burst (8 dwordx4 per lane, contiguous per row)
        f32x4 q0 = *(const f32x4*)(p);       f32x4 q1 = *(const f32x4*)(p + 4);
        f32x4 q2 = *(const f32x4*)(p + 32);  f32x4 q3 = *(const f32x4*)(p + 36);
        f32x4 q4 = *(const f32x4*)(p + 64);  f32x4 q5 = *(const f32x4*)(p + 68);
        f32x4 q6 = *(const f32x4*)(p + 96);  f32x4 q7 = *(const f32x4*)(p + 100);

        const bf16* bp = w1c + (size_t)(it * 16 + kg) * 1024 + (size_t)r16 * 8;
        {   // sub-window 0
            s16x8 a = cvt8(q0, q1);
#pragma unroll
            for (int nj = 0; nj < 8; ++nj) {
                s16x8 b = *(const s16x8*)(bp + nj * 128);
                acc1[nj] = __builtin_amdgcn_mfma_f32_16x16x32_bf16(a, b, acc1[nj], 0, 0, 0);
            }
        }
        {   // sub-window 1
            s16x8 a = cvt8(q2, q3);
            const bf16* bq = bp + 4096;
#pragma unroll
            for (int nj = 0; nj < 8; ++nj) {
                s16x8 b = *(const s16x8*)(bq + nj * 128);
                acc1[nj] = __builtin_amdgcn_mfma_f32_16x16x32_bf16(a, b, acc1[nj], 0, 0, 0);
            }
        }
        {   // sub-window 2
            s16x8 a = cvt8(q4, q5);
            const bf16* bq = bp + 8192;
#pragma unroll
            for (int nj = 0; nj < 8; ++nj) {
                s16x8 b = *(const s16x8*)(bq + nj * 128);
                acc1[nj] = __builtin_amdgcn_mfma_f32_16x16x32_bf16(a, b, acc1[nj], 0, 0, 0);
            }
        }
        {   // sub-window 3
            s16x8 a = cvt8(q6, q7);
            const bf16* bq = bp + 12288;
#pragma unroll
            for (int nj = 0; nj < 8; ++nj) {
                s16x8 b = *(const s16x8*)(bq + nj * 128);
                acc1[nj] = __builtin_amdgcn_mfma_f32_16x16x32_bf16(a, b, acc1[nj], 0, 0, 0);
            }
        }
    }
    {   // tail: k = 768..783 (one 32-window; kg 0,1 in range; weights padded)
        const float* p = xa + 768 + kgo;
        f32x4 q0 = (f32x4){0.f,0.f,0.f,0.f}, q1 = q0;
        if (kg < 2) { q0 = *(const f32x4*)(p); q1 = *(const f32x4*)(p + 4); }
        s16x8 a = cvt8(q0, q1);
        const bf16* bp = w1c + (size_t)(96 + kg) * 1024 + (size_t)r16 * 8;
#pragma unroll
        for (int nj = 0; nj < 8; ++nj) {
            s16x8 b = *(const s16x8*)(bp + nj * 128);
            acc1[nj] = __builtin_amdgcn_mfma_f32_16x16x32_bf16(a, b, acc1[nj], 0, 0, 0);
        }
    }

    // bias + relu -> h1 (wave-private). D layout: col = r16, row = kg*4 + r.
    short (*h1)[132] = (short(*)[132])&arena[wv][0];
#pragma unroll
    for (int nj = 0; nj < 8; ++nj) {
        const int col = nj * 16 + r16;
        const float bb = b1[col];
#pragma unroll
        for (int r = 0; r < 4; ++r)
            h1[kg * 4 + r][col] = b2s(fmaxf(acc1[nj][r] + bb, 0.0f));
    }

    // ---- layer 2: [16 x 128] @ [128 x 64] per wave ----
    f32x4 acc2[4];
#pragma unroll
    for (int j = 0; j < 4; ++j) acc2[j] = (f32x4){0.f, 0.f, 0.f, 0.f};

#pragma unroll
    for (int it = 0; it < 4; ++it) {
        const int kk = it * 32 + kgo;
        s16x8 a = *(const s16x8*)&h1[r16][kk];
        const bf16* bp2 = w2c + (size_t)(it * 4 + kg) * 512 + (size_t)r16 * 8;
#pragma unroll
        for (int nj = 0; nj < 4; ++nj) {
            s16x8 b = *(const s16x8*)(bp2 + nj * 128);
            acc2[nj] = __builtin_amdgcn_mfma_f32_16x16x32_bf16(a, b, acc2[nj], 0, 0, 0);
        }
    }

    // h2 overlay (wave-private; same wave finished its h1 reads -> safe)
    short (*h2)[68] = (short(*)[68])&arena[wv][0];
#pragma unroll
    for (int nj = 0; nj < 4; ++nj) {
        const int col = nj * 16 + r16;
        const float bb = b2[col];
#pragma unroll
        for (int r = 0; r < 4; ++r)
            h2[kg * 4 + r][col] = b2s(fmaxf(acc2[nj][r] + bb, 0.0f));
    }

    // ---- layer 3: [16 x 64] @ [64 x 16] (rows 10..15 of W3 are zero) ----
    f32x4 acc3 = (f32x4){0.f, 0.f, 0.f, 0.f};
#pragma unroll
    for (int it = 0; it < 2; ++it) {
        const int kk = it * 32 + kgo;
        s16x8 a = *(const s16x8*)&h2[r16][kk];
        s16x8 b = *(const s16x8*)(w3d + r16 * H2N + kk);
        acc3 = __builtin_amdgcn_mfma_f32_16x16x32_bf16(a, b, acc3, 0, 0, 0);
    }

    // stage f32 outputs in the wave arena, then write this wave's 640 B
    float* ob = (float*)&arena[wv][0];   // 16*10 f32 = 640 B
    const float bb3 = (r16 < OUTN) ? b3[r16] : 0.0f;
#pragma unroll
    for (int r = 0; r < 4; ++r) {
        const int row = kg * 4 + r;
        if (r16 < OUTN) ob[row * OUTN + r16] = acc3[r] + bb3;
    }
    const long long obase = ((long long)blockIdx.x * 64 + wv * 16) * OUTN;
    for (int i = lane; i < 16 * OUTN; i += 64) out[obase + i] = ob[i];
}

extern "C" void kernel_launch(void* const* d_in, const int* in_sizes, int n_in,
                              void* d_out, int out_size, void* d_ws, size_t ws_size,
                              hipStream_t stream) {
    const float* x   = (const float*)d_in[0];
    const int*   w1q = (const int*)d_in[1];
    const float* s1  = (const float*)d_in[2];
    const float* b1  = (const float*)d_in[3];
    const int*   w2q = (const int*)d_in[4];
    const float* s2  = (const float*)d_in[5];
    const float* b2  = (const float*)d_in[6];
    const int*   w3q = (const int*)d_in[7];
    const float* s3  = (const float*)d_in[8];
    const float* b3  = (const float*)d_in[9];
    float* out = (float*)d_out;

    bf16* w1c = (bf16*)d_ws;              // [100][128][8]
    bf16* w2c = w1c + W1C_ELEMS;          // [16][64][8]
    bf16* w3d = w2c + W2C_ELEMS;          // [16][64]

    dequant_kernel<<<128, 256, 0, stream>>>(w1q, s1, w2q, s2, w3q, s3, w1c, w2c, w3d);
    mlp_kernel<<<NROWS / 64, 256, 0, stream>>>(x, w1c, w2c, w3d, b1, b2, b3, out);
}

// Round 7
// 137.541 us; speedup vs baseline: 1.1958x; 1.1248x over previous
//
#include <hip/hip_runtime.h>
#include <hip/hip_bf16.h>

#define NROWS 131072
#define KIN   784
#define H1N   128
#define H2N   64
#define OUTN  10

// chunked weight layouts: w1c[kb][col][8] with kb = k/8  (k in [0,800))
#define W1C_ELEMS (100 * 128 * 8)   // 102400
#define W2C_ELEMS (16 * 64 * 8)     // 8192
#define W3_ELEMS  (16 * 64)         // 1024

typedef short s16x8 __attribute__((ext_vector_type(8)));
typedef float f32x4 __attribute__((ext_vector_type(4)));

typedef __hip_bfloat16 bf16;

static __device__ __forceinline__ short b2s(float f) {
    bf16 h = __float2bfloat16(f);
    return *reinterpret_cast<short*>(&h);
}

static __device__ __forceinline__ s16x8 cvt8(f32x4 a, f32x4 b) {
    s16x8 r;
    r[0] = b2s(a[0]); r[1] = b2s(a[1]); r[2] = b2s(a[2]); r[3] = b2s(a[3]);
    r[4] = b2s(b[0]); r[5] = b2s(b[1]); r[6] = b2s(b[2]); r[7] = b2s(b[3]);
    return r;
}

// async global -> LDS, 16B per lane, per-lane global addr, wave-uniform LDS base
static __device__ __forceinline__ void gl2lds16(const float* g, char* l) {
    __builtin_amdgcn_global_load_lds(
        (const __attribute__((address_space(1))) void*)g,
        (__attribute__((address_space(3))) void*)l, 16, 0, 0);
}

#define WAITV(N) do { asm volatile("s_waitcnt vmcnt(" #N ")" ::: "memory"); \
                      __builtin_amdgcn_sched_barrier(0); } while (0)
#define SBAR() __builtin_amdgcn_sched_barrier(0)

// ---------------- dequant: int4(int32) * f32 scale -> bf16 (chunked layouts) --
__global__ __launch_bounds__(256) void dequant_kernel(
    const int* __restrict__ w1q, const float* __restrict__ s1,
    const int* __restrict__ w2q, const float* __restrict__ s2,
    const int* __restrict__ w3q, const float* __restrict__ s3,
    bf16* __restrict__ w1c, bf16* __restrict__ w2c, bf16* __restrict__ w3d)
{
    const int total = W1C_ELEMS + W2C_ELEMS + W3_ELEMS;
    for (int i = blockIdx.x * blockDim.x + threadIdx.x; i < total;
         i += gridDim.x * blockDim.x) {
        if (i < W1C_ELEMS) {
            int kb = i >> 10, rem = i & 1023;
            int col = rem >> 3, j = rem & 7;
            int k = kb * 8 + j;
            float v = 0.0f;
            if (k < KIN) v = (float)w1q[col * KIN + k] * s1[col];
            w1c[i] = __float2bfloat16(v);
        } else if (i < W1C_ELEMS + W2C_ELEMS) {
            int t = i - W1C_ELEMS;
            int kb = t >> 9, rem = t & 511;
            int col = rem >> 3, j = rem & 7;
            int k = kb * 8 + j;
            w2c[t] = __float2bfloat16((float)w2q[col * H1N + k] * s2[col]);
        } else {
            int t = i - W1C_ELEMS - W2C_ELEMS;
            int r = t >> 6, c = t & 63;
            float v = 0.0f;
            if (r < OUTN) v = (float)w3q[r * H2N + c] * s3[r];
            w3d[t] = __float2bfloat16(v);
        }
    }
}

// ---------------- fused MLP ------------------------------------------------
// 256 threads (4 waves), BM=128, wave owns 32 rows. Layer-1 x is prefetched
// via a per-wave 3-slot global_load_lds ring (4KB/slot, no dest VGPRs), so
// load depth is not VGPR-capped. B-frags load BEFORE ring issue each iter so
// compiler vmcnt waits keep the prefetch airborne. One barrier total; layers
// 2/3 + output run in per-wave LDS arenas overlaying the dead ring.
__global__ __launch_bounds__(256, 3) void mlp_kernel(
    const float* __restrict__ x,
    const bf16*  __restrict__ w1c,
    const bf16*  __restrict__ w2c,
    const bf16*  __restrict__ w3d,
    const float* __restrict__ b1,
    const float* __restrict__ b2,
    const float* __restrict__ b3,
    float* __restrict__ out)
{
    __shared__ __align__(16) char lds[49152];   // ring 3*16KB; arenas overlay

    const int tid  = threadIdx.x;
    const int lane = tid & 63;
    const int wv   = tid >> 6;      // wave 0..3
    const int r16  = lane & 15;
    const int kg   = lane >> 4;     // 0..3
    const int kgo  = kg * 8;

    const long long row0 = (long long)blockIdx.x * 128 + wv * 32;
    const int rl  = lane & 31;      // row within wave
    const int seg = lane >> 5;      // 16B segment 0..1
    const float* gp = x + (row0 + rl) * (long long)KIN + seg * 4;

    char* ringw = lds + (wv << 12); // wave's 4KB lane within each 16KB slot

    // prologue: issue slots 0 and 1 (k-windows 0,1)
    {
        char* l0 = ringw;
        gl2lds16(gp,      l0);
        gl2lds16(gp + 8,  l0 + 1024);
        gl2lds16(gp + 16, l0 + 2048);
        gl2lds16(gp + 24, l0 + 3072);
        const float* g1 = gp + 32;
        char* l1 = ringw + 16384;
        gl2lds16(g1,      l1);
        gl2lds16(g1 + 8,  l1 + 1024);
        gl2lds16(g1 + 16, l1 + 2048);
        gl2lds16(g1 + 24, l1 + 3072);
    }

    // ---- layer 1: [128 x 784] @ [784 x 128], 25 k-windows of 32 ----
    f32x4 acc1[2][8];
#pragma unroll
    for (int i = 0; i < 2; ++i)
#pragma unroll
        for (int j = 0; j < 8; ++j) acc1[i][j] = (f32x4){0.f, 0.f, 0.f, 0.f};

    const bf16* bp = w1c + (size_t)kg * 1024 + (size_t)r16 * 8;
    const int lb = (kg << 10) + (r16 << 4);
    const float* gpi = gp + 64;     // next issue = window 2
    int sc = 0, si = 2;             // consume / issue ring slots

#pragma unroll 1
    for (int it = 0; it < 24; ++it) {
        WAITV(4);                   // slot `it` landed (safety; b-waits also force it)
        const char* sb = ringw + sc * 16384;
        f32x4 q0 = *(const f32x4*)(sb + lb);
        f32x4 q1 = *(const f32x4*)(sb + lb + 512);
        f32x4 q2 = *(const f32x4*)(sb + lb + 256);
        f32x4 q3 = *(const f32x4*)(sb + lb + 768);
        s16x8 a0 = cvt8(q0, q1);
        s16x8 a1 = cvt8(q2, q3);

        // B-frags BEFORE ring issue: their vmcnt waits won't drain the prefetch
        s16x8 bw[8];
#pragma unroll
        for (int nj = 0; nj < 8; ++nj) bw[nj] = *(const s16x8*)(bp + nj * 128);
        SBAR();
        if (it <= 22) {             // issue slot it+2 (slot 24 clamps j=2,3)
            char* li = ringw + si * 16384;
            if (it < 22) {
                gl2lds16(gpi,      li);
                gl2lds16(gpi + 8,  li + 1024);
                gl2lds16(gpi + 16, li + 2048);
                gl2lds16(gpi + 24, li + 3072);
            } else {
                gl2lds16(gpi,       li);
                gl2lds16(gpi + 8,   li + 1024);
                gl2lds16(gpi - 768, li + 2048);   // k>=784: any finite data,
                gl2lds16(gpi - 760, li + 3072);   // weights are zero-padded
            }
            gpi += 32;
        }
        SBAR();
#pragma unroll
        for (int nj = 0; nj < 8; ++nj) {
            acc1[0][nj] = __builtin_amdgcn_mfma_f32_16x16x32_bf16(a0, bw[nj], acc1[0][nj], 0, 0, 0);
            acc1[1][nj] = __builtin_amdgcn_mfma_f32_16x16x32_bf16(a1, bw[nj], acc1[1][nj], 0, 0, 0);
        }
        bp += 4096;
        sc = (sc == 2) ? 0 : sc + 1;
        si = (si == 2) ? 0 : si + 1;
    }
    {   // it = 24 (k 768..799; weights zero for k>=784)
        WAITV(0);
        const char* sb = ringw + sc * 16384;
        f32x4 q0 = *(const f32x4*)(sb + lb);
        f32x4 q1 = *(const f32x4*)(sb + lb + 512);
        f32x4 q2 = *(const f32x4*)(sb + lb + 256);
        f32x4 q3 = *(const f32x4*)(sb + lb + 768);
        s16x8 a0 = cvt8(q0, q1);
        s16x8 a1 = cvt8(q2, q3);
#pragma unroll
        for (int nj = 0; nj < 8; ++nj) {
            s16x8 b = *(const s16x8*)(bp + nj * 128);
            acc1[0][nj] = __builtin_amdgcn_mfma_f32_16x16x32_bf16(a0, b, acc1[0][nj], 0, 0, 0);
            acc1[1][nj] = __builtin_amdgcn_mfma_f32_16x16x32_bf16(a1, b, acc1[1][nj], 0, 0, 0);
        }
    }

    __syncthreads();   // all waves done with the ring -> arenas may overlay

    // ---- per-wave arena (8704 B each): h1[32][132] -> h2[32][68] -> out ----
    char* ar = lds + wv * 8704;
    short (*h1w)[132] = (short(*)[132])ar;
#pragma unroll
    for (int mi = 0; mi < 2; ++mi)
#pragma unroll
        for (int nj = 0; nj < 8; ++nj) {
            const int col = nj * 16 + r16;
            const float bb = b1[col];
#pragma unroll
            for (int r = 0; r < 4; ++r)
                h1w[mi * 16 + kg * 4 + r][col] = b2s(fmaxf(acc1[mi][nj][r] + bb, 0.0f));
        }

    // ---- layer 2: [32 x 128] @ [128 x 64] per wave ----
    f32x4 acc2[2][4];
#pragma unroll
    for (int i = 0; i < 2; ++i)
#pragma unroll
        for (int j = 0; j < 4; ++j) acc2[i][j] = (f32x4){0.f, 0.f, 0.f, 0.f};

#pragma unroll
    for (int it = 0; it < 4; ++it) {
        const int kk = it * 32 + kgo;
        s16x8 a0 = *(const s16x8*)&h1w[r16][kk];
        s16x8 a1 = *(const s16x8*)&h1w[16 + r16][kk];
        const bf16* bp2 = w2c + (size_t)(it * 4 + kg) * 512 + (size_t)r16 * 8;
#pragma unroll
        for (int nj = 0; nj < 4; ++nj) {
            s16x8 b = *(const s16x8*)(bp2 + nj * 128);
            acc2[0][nj] = __builtin_amdgcn_mfma_f32_16x16x32_bf16(a0, b, acc2[0][nj], 0, 0, 0);
            acc2[1][nj] = __builtin_amdgcn_mfma_f32_16x16x32_bf16(a1, b, acc2[1][nj], 0, 0, 0);
        }
    }

    short (*h2w)[68] = (short(*)[68])ar;   // overlay (same-wave reads done)
#pragma unroll
    for (int mi = 0; mi < 2; ++mi)
#pragma unroll
        for (int nj = 0; nj < 4; ++nj) {
            const int col = nj * 16 + r16;
            const float bb = b2[col];
#pragma unroll
            for (int r = 0; r < 4; ++r)
                h2w[mi * 16 + kg * 4 + r][col] = b2s(fmaxf(acc2[mi][nj][r] + bb, 0.0f));
        }

    // ---- layer 3: [32 x 64] @ [64 x 16] (rows 10..15 of W3 are zero) ----
    f32x4 acc3[2];
#pragma unroll
    for (int i = 0; i < 2; ++i) acc3[i] = (f32x4){0.f, 0.f, 0.f, 0.f};

#pragma unroll
    for (int it = 0; it < 2; ++it) {
        const int kk = it * 32 + kgo;
        s16x8 a0 = *(const s16x8*)&h2w[r16][kk];
        s16x8 a1 = *(const s16x8*)&h2w[16 + r16][kk];
        s16x8 b  = *(const s16x8*)(w3d + r16 * H2N + kk);
        acc3[0] = __builtin_amdgcn_mfma_f32_16x16x32_bf16(a0, b, acc3[0], 0, 0, 0);
        acc3[1] = __builtin_amdgcn_mfma_f32_16x16x32_bf16(a1, b, acc3[1], 0, 0, 0);
    }

    float* ob = (float*)ar;   // 32*10 f32 = 1280 B, overlay after h2 reads
    const float bb3 = (r16 < OUTN) ? b3[r16] : 0.0f;
#pragma unroll
    for (int mi = 0; mi < 2; ++mi)
#pragma unroll
        for (int r = 0; r < 4; ++r) {
            const int row = mi * 16 + kg * 4 + r;
            if (r16 < OUTN) ob[row * OUTN + r16] = acc3[mi][r] + bb3;
        }

    const long long obase = row0 * OUTN;   // wave-private rows -> no barrier
    for (int i = lane; i < 32 * OUTN; i += 64) out[obase + i] = ob[i];
}

extern "C" void kernel_launch(void* const* d_in, const int* in_sizes, int n_in,
                              void* d_out, int out_size, void* d_ws, size_t ws_size,
                              hipStream_t stream) {
    const float* x   = (const float*)d_in[0];
    const int*   w1q = (const int*)d_in[1];
    const float* s1  = (const float*)d_in[2];
    const float* b1  = (const float*)d_in[3];
    const int*   w2q = (const int*)d_in[4];
    const float* s2  = (const float*)d_in[5];
    const float* b2  = (const float*)d_in[6];
    const int*   w3q = (const int*)d_in[7];
    const float* s3  = (const float*)d_in[8];
    const float* b3  = (const float*)d_in[9];
    float* out = (float*)d_out;

    bf16* w1c = (bf16*)d_ws;              // [100][128][8]
    bf16* w2c = w1c + W1C_ELEMS;          // [16][64][8]
    bf16* w3d = w2c + W2C_ELEMS;          // [16][64]

    dequant_kernel<<<128, 256, 0, stream>>>(w1q, s1, w2q, s2, w3q, s3, w1c, w2c, w3d);
    mlp_kernel<<<NROWS / 128, 256, 0, stream>>>(x, w1c, w2c, w3d, b1, b2, b3, out);
}

// Round 8
// 111.999 us; speedup vs baseline: 1.4685x; 1.2281x over previous
//
#include <hip/hip_runtime.h>
#include <hip/hip_bf16.h>

#define NROWS 131072
#define KIN   784
#define H1N   128
#define H2N   64
#define OUTN  10

// chunked weight layouts: w1c[kb][col][8] with kb = k/8  (k in [0,800))
#define W1C_ELEMS (100 * 128 * 8)   // 102400
#define W2C_ELEMS (16 * 64 * 8)     // 8192
#define W3_ELEMS  (16 * 64)         // 1024

typedef short s16x8 __attribute__((ext_vector_type(8)));
typedef float f32x4 __attribute__((ext_vector_type(4)));

typedef __hip_bfloat16 bf16;

static __device__ __forceinline__ short b2s(float f) {
    bf16 h = __float2bfloat16(f);
    return *reinterpret_cast<short*>(&h);
}

static __device__ __forceinline__ s16x8 cvt8(f32x4 a, f32x4 b) {
    s16x8 r;
    r[0] = b2s(a[0]); r[1] = b2s(a[1]); r[2] = b2s(a[2]); r[3] = b2s(a[3]);
    r[4] = b2s(b[0]); r[5] = b2s(b[1]); r[6] = b2s(b[2]); r[7] = b2s(b[3]);
    return r;
}

// async global -> LDS: 16B/lane, per-lane global addr, wave-uniform LDS base
static __device__ __forceinline__ void gl2lds16(const void* g, char* l) {
    __builtin_amdgcn_global_load_lds(
        (const __attribute__((address_space(1))) void*)g,
        (__attribute__((address_space(3))) void*)l, 16, 0, 0);
}

#define WAITV(N) do { asm volatile("s_waitcnt vmcnt(" #N ")" ::: "memory"); \
                      __builtin_amdgcn_sched_barrier(0); } while (0)
#define WAITL()  do { asm volatile("s_waitcnt lgkmcnt(0)" ::: "memory"); \
                      __builtin_amdgcn_sched_barrier(0); } while (0)
#define BAR()    __builtin_amdgcn_s_barrier()

// ---------------- dequant: int4(int32) * f32 scale -> bf16 (chunked layouts) --
__global__ __launch_bounds__(256) void dequant_kernel(
    const int* __restrict__ w1q, const float* __restrict__ s1,
    const int* __restrict__ w2q, const float* __restrict__ s2,
    const int* __restrict__ w3q, const float* __restrict__ s3,
    bf16* __restrict__ w1c, bf16* __restrict__ w2c, bf16* __restrict__ w3d)
{
    const int total = W1C_ELEMS + W2C_ELEMS + W3_ELEMS;
    for (int i = blockIdx.x * blockDim.x + threadIdx.x; i < total;
         i += gridDim.x * blockDim.x) {
        if (i < W1C_ELEMS) {
            int kb = i >> 10, rem = i & 1023;
            int col = rem >> 3, j = rem & 7;
            int k = kb * 8 + j;
            float v = 0.0f;
            if (k < KIN) v = (float)w1q[col * KIN + k] * s1[col];
            w1c[i] = __float2bfloat16(v);
        } else if (i < W1C_ELEMS + W2C_ELEMS) {
            int t = i - W1C_ELEMS;
            int kb = t >> 9, rem = t & 511;
            int col = rem >> 3, j = rem & 7;
            int k = kb * 8 + j;
            w2c[t] = __float2bfloat16((float)w2q[col * H1N + k] * s2[col]);
        } else {
            int t = i - W1C_ELEMS - W2C_ELEMS;
            int r = t >> 6, c = t & 63;
            float v = 0.0f;
            if (r < OUTN) v = (float)w3q[r * H2N + c] * s3[r];
            w3d[t] = __float2bfloat16(v);
        }
    }
}

// ---------------- fused MLP ------------------------------------------------
// 256 threads (4 waves), BM=64 rows/block, wave owns 16 rows. Layer-1 A and
// W1 are BOTH staged via global_load_lds into a 2-slot block ring (A 8KB +
// B 8KB per slot); the per-wave vmem stream is a uniform 4-op/window gl_lds
// sequence, so WAITV(4) keeps ~2 windows airborne through compute. Raw
// s_barrier (no vmcnt drain) + per-wave lgkmcnt fences. LDS 32KB -> 5
// blocks/CU (20 waves). B-frags come from LDS (ds_read) -> VGPR ~90.
__global__ __launch_bounds__(256, 5) void mlp_kernel(
    const float* __restrict__ x,
    const bf16*  __restrict__ w1c,
    const bf16*  __restrict__ w2c,
    const bf16*  __restrict__ w3d,
    const float* __restrict__ b1,
    const float* __restrict__ b2,
    const float* __restrict__ b3,
    float* __restrict__ out)
{
    __shared__ __align__(16) char lds[32768];
    // slot s at lds+s*16384: A [0,8192) (wave wv at +wv*2048, 16 rows x 128B,
    // seg-swizzled), B [8192,16384) = verbatim w1c k-window (4 kb-chunks).
    // post-loop arenas: lds + wv*4224 (4224B/wave, ring is dead by then).

    const int tid  = threadIdx.x;
    const int lane = tid & 63;
    const int wv   = tid >> 6;
    const int r16  = lane & 15;
    const int kg   = lane >> 4;     // 0..3
    const int kgo  = kg * 8;

    const int i3 = lane >> 3;       // staging row-in-group 0..7
    const int i7 = lane & 7;        // staging LDS seg slot 0..7
    const int sw = i7 ^ (i3 & 7);   // swizzled global seg index

    const long long rowW = (long long)blockIdx.x * 64 + wv * 16;
    const float* gA0 = x + (rowW + i3) * (long long)KIN + sw * 4;      // rows 0-7
    const float* gA1 = x + (rowW + 8 + i3) * (long long)KIN + sw * 4;  // rows 8-15
    const bf16*  gB  = w1c + (size_t)wv * 1024 + (size_t)lane * 8;     // wave's 2 B-instr base

    // consume offsets (seg-swizzled A; B verbatim chunked)
    const int aoff0 = wv * 2048 + r16 * 128 + (((2 * kg)     ^ (r16 & 7)) * 16);
    const int aoff1 = wv * 2048 + r16 * 128 + (((2 * kg + 1) ^ (r16 & 7)) * 16);
    const int boff  = 8192 + kg * 2048 + r16 * 16;

    // prologue: stage windows 0,1 into slots 0,1 (4 gl_lds each per wave)
#pragma unroll
    for (int w = 0; w < 2; ++w) {
        char* sd = lds + w * 16384;
        gl2lds16(gA0 + w * 32, sd + wv * 2048);
        gl2lds16(gA1 + w * 32, sd + wv * 2048 + 1024);
        const bf16* gw = gB + (size_t)w * 4096;
        gl2lds16(gw,       sd + 8192 + wv * 2048);
        gl2lds16(gw + 512, sd + 8192 + wv * 2048 + 1024);
    }

    f32x4 acc1[8];
#pragma unroll
    for (int j = 0; j < 8; ++j) acc1[j] = (f32x4){0.f, 0.f, 0.f, 0.f};

#pragma unroll 1
    for (int t = 0; t < 24; ++t) {
        WAITV(4);                 // this wave's window-t gl_lds retired
        BAR();                    // all waves' shares landed
        const char* sb = lds + (t & 1) * 16384;
        f32x4 q0 = *(const f32x4*)(sb + aoff0);
        f32x4 q1 = *(const f32x4*)(sb + aoff1);
        s16x8 bw[8];
#pragma unroll
        for (int nj = 0; nj < 8; ++nj)
            bw[nj] = *(const s16x8*)(sb + boff + nj * 256);
        WAITL();                  // reads are in registers
        BAR();                    // all waves done reading slot t&1
        char* sd = lds + (t & 1) * 16384;
        const int w = t + 2;
        if (w < 24) {
            gl2lds16(gA0 + w * 32, sd + wv * 2048);
            gl2lds16(gA1 + w * 32, sd + wv * 2048 + 1024);
            const bf16* gw = gB + (size_t)w * 4096;
            gl2lds16(gw,       sd + 8192 + wv * 2048);
            gl2lds16(gw + 512, sd + 8192 + wv * 2048 + 1024);
        } else if (w == 24) {     // tail window: segs 4-7 redirect in-bounds
            const int adj = (sw >= 4) ? 16 : 0;
            gl2lds16(gA0 + 768 - adj, sd + wv * 2048);
            gl2lds16(gA1 + 768 - adj, sd + wv * 2048 + 1024);
            const bf16* gw = gB + (size_t)24 * 4096;
            gl2lds16(gw,       sd + 8192 + wv * 2048);
            gl2lds16(gw + 512, sd + 8192 + wv * 2048 + 1024);
        }
        s16x8 a = cvt8(q0, q1);
#pragma unroll
        for (int nj = 0; nj < 8; ++nj)
            acc1[nj] = __builtin_amdgcn_mfma_f32_16x16x32_bf16(a, bw[nj], acc1[nj], 0, 0, 0);
    }
    {   // peeled window 24 (k 768-799; weights zero for k>=784)
        WAITV(0);
        BAR();
        const char* sb = lds;     // slot 0
        f32x4 q0 = *(const f32x4*)(sb + aoff0);
        f32x4 q1 = *(const f32x4*)(sb + aoff1);
        s16x8 bw[8];
#pragma unroll
        for (int nj = 0; nj < 8; ++nj)
            bw[nj] = *(const s16x8*)(sb + boff + nj * 256);
        WAITL();
        BAR();                    // ring fully dead -> arenas may overlay
        s16x8 a = cvt8(q0, q1);
#pragma unroll
        for (int nj = 0; nj < 8; ++nj)
            acc1[nj] = __builtin_amdgcn_mfma_f32_16x16x32_bf16(a, bw[nj], acc1[nj], 0, 0, 0);
    }

    // ---- per-wave arena: h1[16][132] -> h2[16][68] -> out stage -------------
    char* ar = lds + wv * 4224;
    short (*h1w)[132] = (short(*)[132])ar;
#pragma unroll
    for (int nj = 0; nj < 8; ++nj) {
        const int col = nj * 16 + r16;
        const float bb = b1[col];
#pragma unroll
        for (int r = 0; r < 4; ++r)
            h1w[kg * 4 + r][col] = b2s(fmaxf(acc1[nj][r] + bb, 0.0f));
    }

    // ---- layer 2: [16 x 128] @ [128 x 64] per wave ----
    f32x4 acc2[4];
#pragma unroll
    for (int j = 0; j < 4; ++j) acc2[j] = (f32x4){0.f, 0.f, 0.f, 0.f};

#pragma unroll
    for (int it = 0; it < 4; ++it) {
        const int kk = it * 32 + kgo;
        s16x8 a = *(const s16x8*)&h1w[r16][kk];
        const bf16* bp2 = w2c + (size_t)(it * 4 + kg) * 512 + (size_t)r16 * 8;
#pragma unroll
        for (int nj = 0; nj < 4; ++nj) {
            s16x8 b = *(const s16x8*)(bp2 + nj * 128);
            acc2[nj] = __builtin_amdgcn_mfma_f32_16x16x32_bf16(a, b, acc2[nj], 0, 0, 0);
        }
    }

    short (*h2w)[68] = (short(*)[68])ar;   // same-wave overlay
#pragma unroll
    for (int nj = 0; nj < 4; ++nj) {
        const int col = nj * 16 + r16;
        const float bb = b2[col];
#pragma unroll
        for (int r = 0; r < 4; ++r)
            h2w[kg * 4 + r][col] = b2s(fmaxf(acc2[nj][r] + bb, 0.0f));
    }

    // ---- layer 3: [16 x 64] @ [64 x 16] (rows 10..15 of W3 are zero) ----
    f32x4 acc3 = (f32x4){0.f, 0.f, 0.f, 0.f};
#pragma unroll
    for (int it = 0; it < 2; ++it) {
        const int kk = it * 32 + kgo;
        s16x8 a = *(const s16x8*)&h2w[r16][kk];
        s16x8 b = *(const s16x8*)(w3d + r16 * H2N + kk);
        acc3 = __builtin_amdgcn_mfma_f32_16x16x32_bf16(a, b, acc3, 0, 0, 0);
    }

    float* ob = (float*)ar;   // 640B, overlay after h2 reads (same wave)
    const float bb3 = (r16 < OUTN) ? b3[r16] : 0.0f;
#pragma unroll
    for (int r = 0; r < 4; ++r) {
        const int row = kg * 4 + r;
        if (r16 < OUTN) ob[row * OUTN + r16] = acc3[r] + bb3;
    }
    const long long obase = rowW * OUTN;
    for (int i = lane; i < 16 * OUTN; i += 64) out[obase + i] = ob[i];
}

extern "C" void kernel_launch(void* const* d_in, const int* in_sizes, int n_in,
                              void* d_out, int out_size, void* d_ws, size_t ws_size,
                              hipStream_t stream) {
    const float* x   = (const float*)d_in[0];
    const int*   w1q = (const int*)d_in[1];
    const float* s1  = (const float*)d_in[2];
    const float* b1  = (const float*)d_in[3];
    const int*   w2q = (const int*)d_in[4];
    const float* s2  = (const float*)d_in[5];
    const float* b2  = (const float*)d_in[6];
    const int*   w3q = (const int*)d_in[7];
    const float* s3  = (const float*)d_in[8];
    const float* b3  = (const float*)d_in[9];
    float* out = (float*)d_out;

    bf16* w1c = (bf16*)d_ws;              // [100][128][8]
    bf16* w2c = w1c + W1C_ELEMS;          // [16][64][8]
    bf16* w3d = w2c + W2C_ELEMS;          // [16][64]

    dequant_kernel<<<128, 256, 0, stream>>>(w1q, s1, w2q, s2, w3q, s3, w1c, w2c, w3d);
    mlp_kernel<<<NROWS / 64, 256, 0, stream>>>(x, w1c, w2c, w3d, b1, b2, b3, out);
}